// Round 1
// baseline (298.495 us; speedup 1.0000x reference)
//
#include <hip/hip_runtime.h>

// Conv bank of 17 fixed filters + ReLU over (128,1,32768) fp32.
// out[b,j,t] = relu( sum_k W[j,k] * x_pad[b, t+k-47] ), pad (47,48).
//
// Structure used (weights are deterministic from the reference):
//  - j=0..5  : alternating +-1 filters K=2,4,8,16,32,64  (f[even]=-1)
//  - j=6..11 : exact negations of j=0..5
//  - j=12..16: quadratic-bump filters, span 3K/2 for K=4,8,16,32,64,
//              pattern [-L,-R, 2L,2R, -L,-R], L_i=((i+1)/q)^2, q=K/4, R=rev(L)
//
// Alternating filters via local alternating prefix sum Q (2 LDS reads + 1 sub each).
// Bump filters via direct FMA with compile-time literal weights, 4 consecutive
// positions per thread sharing every x read (rolling-weight formulation).
// LDS plane-split layout ((j&3)*PITCH + j>>2) makes all compute-phase reads
// stride-1 across lanes (conflict-free) with compile-time immediate offsets.

#define S_LEN   32768
#define NFILT   17
#define TILE    1024
#define HALO_L  47
#define WIN     (TILE + 96)    // 1120 staged x values per block
#define NCHUNK  (WIN / 8)      // 140 scan chunks of 8
#define PITCH   284            // per-plane pitch (>= 281 needed)
#define NTHREADS 256

template<int Q>
__device__ __forceinline__ float third_w(int j) {
    // weight j (0..6Q-1) of the bump filter with q=Q; exact vs numpy:
    // (i+1)/Q exact (Q power of 2), square rounds identically in fp32.
    constexpr float inv = 1.0f / (float)Q;
    const int seg = j / Q;
    const int i = j - seg * Q;
    const float t = (seg == 0 || seg == 2 || seg == 4) ? (float)(i + 1) * inv
                                                       : (float)(Q - i) * inv;
    const float v = t * t;
    return (seg == 2 || seg == 3) ? 2.0f * v : -v;
}

template<int K>
__device__ __forceinline__ float4 third_acc(const float* __restrict__ xsp, int tid) {
    constexpr int Q    = K / 4;
    constexpr int SPAN = 6 * Q;               // filter length 3K/2
    constexpr int C    = (3 * K / 2 - 1) / 2; // left reach from center
    float a0 = 0.f, a1 = 0.f, a2 = 0.f, a3 = 0.f;
#pragma unroll
    for (int u = 0; u < SPAN + 3; ++u) {
        const int d = (HALO_L - C) + u;       // logical xs index = 4*tid + d
        const float xv = xsp[(d & 3) * PITCH + tid + (d >> 2)];
        if (u < SPAN)               a0 = fmaf(third_w<Q>(u),     xv, a0);
        if (u >= 1 && u - 1 < SPAN) a1 = fmaf(third_w<Q>(u - 1), xv, a1);
        if (u >= 2 && u - 2 < SPAN) a2 = fmaf(third_w<Q>(u - 2), xv, a2);
        if (u >= 3 && u - 3 < SPAN) a3 = fmaf(third_w<Q>(u - 3), xv, a3);
    }
    return make_float4(a0, a1, a2, a3);
}

template<int K>
__device__ __forceinline__ float4 alt_acc(const float* __restrict__ Qsp, int tid) {
    // A_K(t) for 4 consecutive t via alternating-prefix differences.
    constexpr int H = (K - 1) / 2;
    float v[4];
#pragma unroll
    for (int r = 0; r < 4; ++r) {
        const int d  = HALO_L + r - H;        // window start m = 4*tid + d
        const int d2 = d + K;
        const float qa = Qsp[(d  & 3) * PITCH + tid + (d  >> 2)];
        const float qb = Qsp[(d2 & 3) * PITCH + tid + (d2 >> 2)];
        const float dd = qb - qa;
        v[r] = (d & 1) ? dd : -dd;            // parity fixed at compile time
    }
    return make_float4(v[0], v[1], v[2], v[3]);
}

__global__ __launch_bounds__(NTHREADS)
void conv_bank_kernel(const float* __restrict__ x, float* __restrict__ out) {
    __shared__ float xsp[4 * PITCH];
    __shared__ float Qsp[4 * PITCH];
    __shared__ float scanb[NTHREADS];

    const int tid = threadIdx.x;
    const int ts  = blockIdx.x * TILE;
    const int b   = blockIdx.y;
    const float* __restrict__ xrow = x + (size_t)b * S_LEN;

    // ---- stage x tile + halo (zero-padded at row edges) ----
    for (int j = tid; j < WIN; j += NTHREADS) {
        const int g = ts - HALO_L + j;
        float v = 0.f;
        if ((unsigned)g < (unsigned)S_LEN) v = xrow[g];
        xsp[(j & 3) * PITCH + (j >> 2)] = v;
    }
    __syncthreads();

    // ---- local alternating prefix sum Q[i] = sum_{k<i} (-1)^k xs[k] ----
    float csum = 0.f;
    if (tid < NCHUNK) {
#pragma unroll
        for (int k = 0; k < 8; ++k) {
            const float v = xsp[(k & 3) * PITCH + 2 * tid + (k >> 2)];
            csum += (k & 1) ? -v : v;
        }
    }
    scanb[tid] = csum;
    __syncthreads();
    float incl = csum;
#pragma unroll
    for (int off = 1; off < NTHREADS; off <<= 1) {
        const float add = (tid >= off) ? scanb[tid - off] : 0.f;
        __syncthreads();
        incl += add;
        scanb[tid] = incl;
        __syncthreads();
    }
    if (tid < NCHUNK) {
        float run = incl - csum;              // exclusive chunk prefix
#pragma unroll
        for (int k = 0; k < 8; ++k) {
            const int idx = (k & 3) * PITCH + 2 * tid + (k >> 2);
            Qsp[idx] = run;
            const float v = xsp[idx];
            run += (k & 1) ? -v : v;
        }
        if (tid == NCHUNK - 1) Qsp[WIN >> 2] = run;   // Q[1120] -> plane0, 280
    }
    __syncthreads();

    // ---- compute 17 outputs for 4 consecutive positions, relu, float4 store ----
    const int t0 = ts + 4 * tid;
    float* __restrict__ obase = out + (size_t)b * NFILT * S_LEN + t0;

    auto store_relu = [&](int j, float4 v) {
        float4 s;
        s.x = fmaxf(v.x, 0.f); s.y = fmaxf(v.y, 0.f);
        s.z = fmaxf(v.z, 0.f); s.w = fmaxf(v.w, 0.f);
        *reinterpret_cast<float4*>(obase + (size_t)j * S_LEN) = s;
    };
    auto store_pair = [&](int j, float4 a) {
        store_relu(j, a);
        store_relu(j + 6, make_float4(-a.x, -a.y, -a.z, -a.w));
    };

    store_pair(0, alt_acc<2 >(Qsp, tid));
    store_pair(1, alt_acc<4 >(Qsp, tid));
    store_pair(2, alt_acc<8 >(Qsp, tid));
    store_pair(3, alt_acc<16>(Qsp, tid));
    store_pair(4, alt_acc<32>(Qsp, tid));
    store_pair(5, alt_acc<64>(Qsp, tid));

    store_relu(12, third_acc<4 >(xsp, tid));
    store_relu(13, third_acc<8 >(xsp, tid));
    store_relu(14, third_acc<16>(xsp, tid));
    store_relu(15, third_acc<32>(xsp, tid));
    store_relu(16, third_acc<64>(xsp, tid));
}

extern "C" void kernel_launch(void* const* d_in, const int* in_sizes, int n_in,
                              void* d_out, int out_size, void* d_ws, size_t ws_size,
                              hipStream_t stream) {
    const float* x = (const float*)d_in[0];
    float* out = (float*)d_out;
    const int nbatch = in_sizes[0] / S_LEN;   // 128
    dim3 grid(S_LEN / TILE, nbatch, 1);
    conv_bank_kernel<<<grid, NTHREADS, 0, stream>>>(x, out);
}